// Round 1
// baseline (120.088 us; speedup 1.0000x reference)
//
#include <hip/hip_runtime.h>
#include <cmath>

#define NKEY 3072
#define KSEL 100
#define TTOP 512
#define TITER (NKEY / TTOP)   // 6
#define PCHUNK 128            // preds per k_maxiou block; grid.y = 6400/128 = 50
#define ICHUNK 128            // confs per k_pair block;  grid.y = 50
#define NPAIRBLK (25 * 50)    // 1250 pair blocks

static __device__ __forceinline__ float sigf(float v) {
    return 1.0f / (1.0f + expf(-v));
}

// Block sum-reduction in double for NWAVE waves. Valid result on thread 0.
// Leading barrier makes back-to-back calls safe.
template <int NWAVE>
static __device__ double block_reduce_sum(double v) {
    __shared__ double sh[NWAVE];
    __syncthreads();
    for (int off = 32; off > 0; off >>= 1) v += __shfl_down(v, off, 64);
    int lane = threadIdx.x & 63, wid = threadIdx.x >> 6;
    if (lane == 0) sh[wid] = v;
    __syncthreads();
    v = (threadIdx.x < NWAVE) ? sh[threadIdx.x] : 0.0;
    if (wid == 0) {
        #pragma unroll
        for (int off = NWAVE / 2; off > 0; off >>= 1) v += __shfl_down(v, off, 64);
    }
    return v;
}

// ---------------------------------------------------------------------------
// k_topk: per-batch (64 blocks, 512 threads) --
//   * build u64 keys (conf_bits<<32 | ~idx) for 3072 cells, accumulate
//     negative-size penalty partial
//   * radix-select the exact 100th-largest key (top_k semantics: descending
//     value, ties -> lower index; key packing encodes this)
//   * compact the 100 selected keys, rank by counting, write pred corners /
//     conf in sorted order; fix target boxes; zero maxiou_bits slice;
//     block 0 zeros the pair-sum accumulator + completion counter
// ---------------------------------------------------------------------------
__global__ __launch_bounds__(TTOP) void k_topk(const float* __restrict__ pred,
                                               const float* __restrict__ tgt,
                                               float* __restrict__ predc,
                                               float* __restrict__ targc,
                                               float* __restrict__ confv,
                                               unsigned int* __restrict__ maxiou_bits,
                                               double* __restrict__ negp /*[64]*/,
                                               double* __restrict__ pairSum,
                                               unsigned int* __restrict__ pcnt) {
    const int b = blockIdx.x;
    const int t = threadIdx.x;

    __shared__ unsigned long long keys[NKEY];   // 24 KB
    __shared__ unsigned int hist[256];
    __shared__ unsigned long long sel[KSEL];
    __shared__ unsigned long long tkey_sh;
    __shared__ unsigned int scnt;
    __shared__ int bdigit_sh;
    __shared__ int bk_sh;

    if (b == 0 && t == 0) { *pairSum = 0.0; *pcnt = 0u; }

    // ---- target box fixing (epsilon = 1.0) + maxiou init ----
    if (t < KSEL) {
        int n = b * KSEL + t;
        const float* tb = tgt + (size_t)n * 4;
        float a0 = tb[0], a1 = tb[1], a2 = tb[2], a3 = tb[3];
        float x1 = fminf(a0, a2), y1 = fminf(a1, a3);
        float x2 = fmaxf(a0, a2), y2 = fmaxf(a1, a3);
        if (x1 == x2) x2 = x1 + 1.0f;
        if (y1 == y2) y2 = y1 + 1.0f;
        targc[n * 4 + 0] = x1; targc[n * 4 + 1] = y1;
        targc[n * 4 + 2] = x2; targc[n * 4 + 3] = y2;
        maxiou_bits[n] = 0u;
    }
    if (t == 0) scnt = 0;

    // ---- phase A: keys + negpen partial ----
    const float* pb = pred + (size_t)b * (NKEY * 5);
    float negacc = 0.0f;
    for (int r = 0; r < TITER; ++r) {
        int idx = t + r * TTOP;
        const float* pe = pb + (size_t)idx * 5;
        float w = pe[2], h = pe[3], cl = pe[4];
        negacc += fmaxf(1.0f - w, 0.0f) + fmaxf(1.0f - h, 0.0f);
        float c = sigf(cl);
        keys[idx] = ((unsigned long long)__float_as_uint(c) << 32)
                  | (unsigned long long)(0xFFFFFFFFu - (unsigned)idx);
    }
    {
        double v = block_reduce_sum<8>((double)negacc);  // has its own barriers
        if (t == 0) negp[b] = v;
    }
    __syncthreads();  // keys + scnt visible

    // ---- phase B: radix select (MSB-first 8-bit digits) ----
    unsigned long long prefix = 0ull;
    int plen = 0;       // matched high bits
    int k = KSEL;       // rank within prefix-matched subset
    bool done = false;
    for (int round = 0; round < 8 && !done; ++round) {
        if (t < 256) hist[t] = 0u;
        __syncthreads();
        int shift = 56 - 8 * round;
        for (int r = 0; r < TITER; ++r) {
            unsigned long long key = keys[t + r * TTOP];
            if (plen == 0 || (key >> (64 - plen)) == (prefix >> (64 - plen))) {
                atomicAdd(&hist[(unsigned)((key >> shift) & 0xFFull)], 1u);
            }
        }
        __syncthreads();
        if (t < 64) {  // wave 0: suffix-scan the 256-bin histogram
            unsigned s0 = hist[4 * t + 0], s1 = hist[4 * t + 1];
            unsigned s2 = hist[4 * t + 2], s3 = hist[4 * t + 3];
            unsigned ssum = s0 + s1 + s2 + s3;
            unsigned suf = ssum;  // inclusive suffix sum across lanes
            for (int off = 1; off < 64; off <<= 1) {
                unsigned o = __shfl_down(suf, off, 64);
                if (t + off < 64) suf += o;
            }
            unsigned above = suf - ssum;  // keys with digit >= 4(t+1)
            if (above < (unsigned)k && suf >= (unsigned)k) {
                unsigned hh[4] = {s0, s1, s2, s3};
                unsigned cum = above;
                for (int q = 3; q >= 0; --q) {
                    unsigned c = hh[q];
                    if (cum + c >= (unsigned)k) { bdigit_sh = 4 * t + q; bk_sh = k - (int)cum; break; }
                    cum += c;
                }
            }
        }
        __syncthreads();
        int d = bdigit_sh;
        k = bk_sh;
        prefix |= ((unsigned long long)(unsigned)d) << shift;
        plen += 8;
        unsigned ceq = hist[d];
        if (ceq == 1u) {  // unique bucket: the 100th key is determined
            for (int r = 0; r < TITER; ++r) {
                unsigned long long key = keys[t + r * TTOP];
                if ((key >> (64 - plen)) == (prefix >> (64 - plen))) tkey_sh = key;
            }
            done = true;  // uniform (ceq is uniform)
        }
        __syncthreads();
    }
    // round 7 examines the full key (all keys unique) => tkey_sh always set
    unsigned long long T = tkey_sh;

    // ---- phase C: compact + rank + emit ----
    for (int r = 0; r < TITER; ++r) {
        unsigned long long key = keys[t + r * TTOP];
        if (key >= T) {
            unsigned pos = atomicAdd(&scnt, 1u);  // exactly 100 total
            sel[pos] = key;
        }
    }
    __syncthreads();
    if (t < KSEL) {
        unsigned long long key = sel[t];
        int rank = 0;
        for (int p = 0; p < KSEL; ++p) rank += (sel[p] > key) ? 1 : 0;
        unsigned idx = 0xFFFFFFFFu - (unsigned)(key & 0xFFFFFFFFull);
        float conf = __uint_as_float((unsigned)(key >> 32));
        int n = b * KSEL + rank;
        confv[n] = conf;
        const float* pe = pb + (size_t)idx * 5;
        int w = idx & 31, h = (idx >> 5) & 31;  // flat = a*1024 + h*32 + w
        float x  = (sigf(pe[0]) + (float)w) * 32.0f;
        float y  = (sigf(pe[1]) + (float)h) * 32.0f;
        float bw = expf(pe[2]) * 32.0f;
        float bh = expf(pe[3]) * 32.0f;
        predc[n * 4 + 0] = x - bw * 0.5f;
        predc[n * 4 + 1] = y - bh * 0.5f;
        predc[n * 4 + 2] = x + bw * 0.5f;
        predc[n * 4 + 3] = y + bh * 0.5f;
    }
}

// ---------------------------------------------------------------------------
// k_maxiou: grid (25, 50). block (x, y): targets j in [x*256, x*256+256),
// preds i in [y*128, y*128+128) staged in LDS (boxes + precomputed areas);
// atomicMax (float-as-uint, IoU >= 0). iou via v_rcp_f32: union > 0 strictly
// here (pred areas are exp-products > 0; target boxes epsilon-fixed), ~1 ulp.
// Finer PCHUNK (200->128) smooths CU load: max-loaded CU drops 800->640 iters.
// blockIdx.y == 0 additionally computes paired DIoU and the smooth-L1 partial.
// ---------------------------------------------------------------------------
__global__ __launch_bounds__(256) void k_maxiou(const float* __restrict__ predc,
                                                const float* __restrict__ targc,
                                                unsigned int* __restrict__ maxiou_bits,
                                                float* __restrict__ diouv,
                                                double* __restrict__ sl1p /*[25]*/) {
    __shared__ float4 pl[PCHUNK];
    __shared__ float pa_sh[PCHUNK];
    int t = threadIdx.x;
    int j = blockIdx.x * 256 + t;
    const float4* pc4 = (const float4*)predc;
    int i0 = blockIdx.y * PCHUNK;
    if (t < PCHUNK) {
        float4 p = pc4[i0 + t];
        pl[t] = p;
        pa_sh[t] = (p.z - p.x) * (p.w - p.y);
    }
    float4 tj = ((const float4*)targc)[j];
    float ta = (tj.z - tj.x) * (tj.w - tj.y);
    __syncthreads();
    float m0 = 0.0f, m1 = 0.0f, m2 = 0.0f, m3 = 0.0f;
    #pragma unroll 2
    for (int i = 0; i < PCHUNK; i += 4) {
        {
            float4 p = pl[i];
            float w = fmaxf(fminf(p.z, tj.z) - fmaxf(p.x, tj.x), 0.0f);
            float h = fmaxf(fminf(p.w, tj.w) - fmaxf(p.y, tj.y), 0.0f);
            float in = w * h;
            m0 = fmaxf(m0, in * __builtin_amdgcn_rcpf(pa_sh[i] + ta - in));
        }
        {
            float4 p = pl[i + 1];
            float w = fmaxf(fminf(p.z, tj.z) - fmaxf(p.x, tj.x), 0.0f);
            float h = fmaxf(fminf(p.w, tj.w) - fmaxf(p.y, tj.y), 0.0f);
            float in = w * h;
            m1 = fmaxf(m1, in * __builtin_amdgcn_rcpf(pa_sh[i + 1] + ta - in));
        }
        {
            float4 p = pl[i + 2];
            float w = fmaxf(fminf(p.z, tj.z) - fmaxf(p.x, tj.x), 0.0f);
            float h = fmaxf(fminf(p.w, tj.w) - fmaxf(p.y, tj.y), 0.0f);
            float in = w * h;
            m2 = fmaxf(m2, in * __builtin_amdgcn_rcpf(pa_sh[i + 2] + ta - in));
        }
        {
            float4 p = pl[i + 3];
            float w = fmaxf(fminf(p.z, tj.z) - fmaxf(p.x, tj.x), 0.0f);
            float h = fmaxf(fminf(p.w, tj.w) - fmaxf(p.y, tj.y), 0.0f);
            float in = w * h;
            m3 = fmaxf(m3, in * __builtin_amdgcn_rcpf(pa_sh[i + 3] + ta - in));
        }
    }
    m0 = fmaxf(fmaxf(m0, m1), fmaxf(m2, m3));
    atomicMax(&maxiou_bits[j], __float_as_uint(m0));

    if (blockIdx.y == 0) {
        float4 p = pc4[j];  // paired pred for target j
        float pa = fmaxf(p.z - p.x, 0.f) * fmaxf(p.w - p.y, 0.f);
        float ta2 = fmaxf(tj.z - tj.x, 0.f) * fmaxf(tj.w - tj.y, 0.f);
        float ix1 = fmaxf(p.x, tj.x), iy1 = fmaxf(p.y, tj.y);
        float ix2 = fminf(p.z, tj.z), iy2 = fminf(p.w, tj.w);
        float inter = fmaxf(ix2 - ix1, 0.f) * fmaxf(iy2 - iy1, 0.f);
        float iou = inter / (pa + ta2 - inter + 1e-7f);
        float pcx = (p.x + p.z) * 0.5f, pcy = (p.y + p.w) * 0.5f;
        float tcx = (tj.x + tj.z) * 0.5f, tcy = (tj.y + tj.w) * 0.5f;
        float cd = (pcx - tcx) * (pcx - tcx) + (pcy - tcy) * (pcy - tcy);
        float ex1 = fminf(p.x, tj.x), ey1 = fminf(p.y, tj.y);
        float ex2 = fmaxf(p.z, tj.z), ey2 = fmaxf(p.w, tj.w);
        float dg = (ex2 - ex1) * (ex2 - ex1) + (ey2 - ey1) * (ey2 - ey1);
        diouv[j] = 1.0f - (iou - cd / (dg + 1e-7f));
        double s = 0.0;
        {
            float d0 = p.x - tj.x, d1 = p.y - tj.y, d2 = p.z - tj.z, d3 = p.w - tj.w;
            float a0 = fabsf(d0), a1 = fabsf(d1), a2 = fabsf(d2), a3 = fabsf(d3);
            s += (double)(a0 < 1.f ? 0.5f * d0 * d0 : a0 - 0.5f);
            s += (double)(a1 < 1.f ? 0.5f * d1 * d1 : a1 - 0.5f);
            s += (double)(a2 < 1.f ? 0.5f * d2 * d2 : a2 - 0.5f);
            s += (double)(a3 < 1.f ? 0.5f * d3 * d3 : a3 - 0.5f);
        }
        double v = block_reduce_sum<4>(s);
        if (t == 0) sl1p[blockIdx.x] = v;
    }
}

// ---------------------------------------------------------------------------
// k_pair: sum over the [N,N] broadcast of good - bad. grid (25 j, 50 i).
// (1-y)^2 precomputed in LDS; raw v_sqrt_f32 (~1 ulp vs 0.28 threshold).
// Block partial goes into one device-scope double atomicAdd; the last block
// to finish (ticket == NPAIRBLK-1) folds in negp and writes the scalar out
// (replaces the former k_final dispatch).
// ---------------------------------------------------------------------------
__global__ __launch_bounds__(256) void k_pair(const unsigned int* __restrict__ maxiou_bits,
                                              const float* __restrict__ diouv,
                                              const float* __restrict__ confv,
                                              const double* __restrict__ sl1p,
                                              const double* __restrict__ negp,
                                              double* __restrict__ pairSum,
                                              unsigned int* __restrict__ pcnt,
                                              float* __restrict__ out) {
    __shared__ float oy2s[ICHUNK];
    __shared__ float sl1_sh;
    __shared__ unsigned int ticket_sh;
    int t = threadIdx.x;
    int j = blockIdx.x * 256 + t;
    if (t == 0) {
        double s = 0.0;
        for (int i = 0; i < 25; ++i) s += sl1p[i];
        sl1_sh = (float)(s / 25600.0 / 512.0);
    }
    if (t < ICHUNK) {
        float oy = 1.0f - confv[blockIdx.y * ICHUNK + t];
        oy2s[t] = oy * oy;
    }
    float mj = __uint_as_float(maxiou_bits[j]);
    float dj = diouv[j];
    __syncthreads();
    float xj = (1.0f - mj) * 2.0f + dj + sl1_sh;
    float a2 = xj * xj;
    float bb = 3.5f - xj;
    float b2 = bb * bb;
    float acc0 = 0.0f, acc1 = 0.0f;
    #pragma unroll 4
    for (int i = 0; i < ICHUNK; i += 2) {
        float o0 = oy2s[i], o1 = oy2s[i + 1];
        acc0 += 2.0f * __builtin_amdgcn_sqrtf(a2 + o0)
              - 1.5f * __builtin_amdgcn_sqrtf(b2 + o0);
        acc1 += 2.0f * __builtin_amdgcn_sqrtf(a2 + o1)
              - 1.5f * __builtin_amdgcn_sqrtf(b2 + o1);
    }
    double v = block_reduce_sum<4>((double)(acc0 + acc1));
    if (t == 0) {
        atomicAdd(pairSum, v);       // device-scope f64 atomic
        __threadfence();
        ticket_sh = atomicAdd(pcnt, 1u);
    }
    __syncthreads();
    if (ticket_sh == (unsigned)(NPAIRBLK - 1)) {
        // last block: all other partials are globally visible (fence+atomic)
        __threadfence();
        double n = (t < 64) ? negp[t] : 0.0;
        double ns = block_reduce_sum<4>(n);
        if (t == 0) {
            double ps = atomicAdd(pairSum, 0.0);           // coherent read
            double mean_pair = ps / 40960000.0;            // 6400*6400
            float losses = fmaxf((float)mean_pair + 5.25f, 0.0f);  // + 3.5*1.5
            float neg = (float)(ns / 196608.0);
            out[0] = losses + neg;
        }
    }
}

// ---------------- launch ----------------

extern "C" void kernel_launch(void* const* d_in, const int* in_sizes, int n_in,
                              void* d_out, int out_size, void* d_ws, size_t ws_size,
                              hipStream_t stream) {
    const float* pred = (const float*)d_in[0];   // [64,3,32,32,5]
    const float* tgt  = (const float*)d_in[1];   // [64,100,4]
    float* out = (float*)d_out;

    char* ws = (char*)d_ws;
    double* negp  = (double*)ws;                 // 64 doubles
    double* sl1p  = negp + 64;                   // 25
    double* pairSum = negp + 96;                 // 1 double
    unsigned int* pcnt = (unsigned int*)(negp + 97);
    float* fbase  = (float*)(ws + 1024);         // 16B-aligned float region
    float* predc  = fbase;                       // 25600 floats
    float* targc  = fbase + 25600;               // 25600
    float* confv  = fbase + 51200;               // 6400
    float* diouv  = fbase + 57600;               // 6400
    unsigned int* maxiou_bits = (unsigned int*)(fbase + 64000);  // 6400

    k_topk<<<64, TTOP, 0, stream>>>(pred, tgt, predc, targc, confv, maxiou_bits,
                                    negp, pairSum, pcnt);
    k_maxiou<<<dim3(25, 6400 / PCHUNK), 256, 0, stream>>>(predc, targc, maxiou_bits,
                                                          diouv, sl1p);
    k_pair<<<dim3(25, 6400 / ICHUNK), 256, 0, stream>>>(maxiou_bits, diouv, confv,
                                                        sl1p, negp, pairSum, pcnt, out);
}

// Round 2
// 100.954 us; speedup vs baseline: 1.1895x; 1.1895x over previous
//
#include <hip/hip_runtime.h>
#include <cmath>

#define NKEY 3072
#define KSEL 100
#define PCHUNK 128            // preds per k_maxiou block; grid.y = 6400/128 = 50
#define ICHUNK 128            // confs per k_pair block;  grid.y = 50
#define NPAIRBLK (25 * 50)    // 1250 pair partials

static __device__ __forceinline__ float sigf(float v) {
    return 1.0f / (1.0f + expf(-v));
}

// Block (256 threads) sum-reduction in double. Valid result on thread 0.
// Leading barrier makes back-to-back calls safe.
static __device__ double block_reduce_sum(double v) {
    __shared__ double sh[4];
    __syncthreads();
    for (int off = 32; off > 0; off >>= 1) v += __shfl_down(v, off, 64);
    int lane = threadIdx.x & 63, wid = threadIdx.x >> 6;
    if (lane == 0) sh[wid] = v;
    __syncthreads();
    v = (threadIdx.x < 4) ? sh[threadIdx.x] : 0.0;
    if (wid == 0) {
        v += __shfl_down(v, 2, 64);
        v += __shfl_down(v, 1, 64);
    }
    return v;
}

// ---------------------------------------------------------------------------
// k_topk: per-batch (64 blocks) --
//   * build u64 keys (conf_bits<<32 | ~idx) for 3072 cells, accumulate
//     negative-size penalty partial (fused: same cache lines)
//   * radix-select the exact 100th-largest key (jax.lax.top_k semantics:
//     descending value, ties -> lower index; key packing encodes this)
//   * compact the 100 selected keys, rank by counting, write pred corners /
//     conf in sorted order; fix target boxes; zero maxiou_bits slice
// ---------------------------------------------------------------------------
__global__ __launch_bounds__(256) void k_topk(const float* __restrict__ pred,
                                              const float* __restrict__ tgt,
                                              float* __restrict__ predc,
                                              float* __restrict__ targc,
                                              float* __restrict__ confv,
                                              unsigned int* __restrict__ maxiou_bits,
                                              double* __restrict__ negp /*[64]*/) {
    const int b = blockIdx.x;
    const int t = threadIdx.x;

    __shared__ unsigned long long keys[NKEY];   // 24 KB
    __shared__ unsigned int hist[256];
    __shared__ unsigned long long sel[KSEL];
    __shared__ unsigned long long tkey_sh;
    __shared__ unsigned int scnt;
    __shared__ int bdigit_sh;
    __shared__ int bk_sh;

    // ---- target box fixing (epsilon = 1.0) + maxiou init ----
    if (t < KSEL) {
        int n = b * KSEL + t;
        const float* tb = tgt + (size_t)n * 4;
        float a0 = tb[0], a1 = tb[1], a2 = tb[2], a3 = tb[3];
        float x1 = fminf(a0, a2), y1 = fminf(a1, a3);
        float x2 = fmaxf(a0, a2), y2 = fmaxf(a1, a3);
        if (x1 == x2) x2 = x1 + 1.0f;
        if (y1 == y2) y2 = y1 + 1.0f;
        targc[n * 4 + 0] = x1; targc[n * 4 + 1] = y1;
        targc[n * 4 + 2] = x2; targc[n * 4 + 3] = y2;
        maxiou_bits[n] = 0u;
    }
    if (t == 0) scnt = 0;

    // ---- phase A: keys + negpen partial ----
    const float* pb = pred + (size_t)b * (NKEY * 5);
    float negacc = 0.0f;
    for (int r = 0; r < 12; ++r) {
        int idx = t + r * 256;
        const float* pe = pb + (size_t)idx * 5;
        float w = pe[2], h = pe[3], cl = pe[4];
        negacc += fmaxf(1.0f - w, 0.0f) + fmaxf(1.0f - h, 0.0f);
        float c = sigf(cl);
        keys[idx] = ((unsigned long long)__float_as_uint(c) << 32)
                  | (unsigned long long)(0xFFFFFFFFu - (unsigned)idx);
    }
    {
        double v = block_reduce_sum((double)negacc);  // has its own barriers
        if (t == 0) negp[b] = v;
    }
    __syncthreads();  // keys + scnt visible

    // ---- phase B: radix select (MSB-first 8-bit digits) ----
    unsigned long long prefix = 0ull;
    int plen = 0;       // matched high bits
    int k = KSEL;       // rank within prefix-matched subset
    bool done = false;
    for (int round = 0; round < 8 && !done; ++round) {
        hist[t] = 0u;
        __syncthreads();
        int shift = 56 - 8 * round;
        for (int r = 0; r < 12; ++r) {
            unsigned long long key = keys[t + r * 256];
            if (plen == 0 || (key >> (64 - plen)) == (prefix >> (64 - plen))) {
                atomicAdd(&hist[(unsigned)((key >> shift) & 0xFFull)], 1u);
            }
        }
        __syncthreads();
        if (t < 64) {  // wave 0: suffix-scan the 256-bin histogram
            unsigned s0 = hist[4 * t + 0], s1 = hist[4 * t + 1];
            unsigned s2 = hist[4 * t + 2], s3 = hist[4 * t + 3];
            unsigned ssum = s0 + s1 + s2 + s3;
            unsigned suf = ssum;  // inclusive suffix sum across lanes
            for (int off = 1; off < 64; off <<= 1) {
                unsigned o = __shfl_down(suf, off, 64);
                if (t + off < 64) suf += o;
            }
            unsigned above = suf - ssum;  // keys with digit >= 4(t+1)
            if (above < (unsigned)k && suf >= (unsigned)k) {
                unsigned hh[4] = {s0, s1, s2, s3};
                unsigned cum = above;
                for (int q = 3; q >= 0; --q) {
                    unsigned c = hh[q];
                    if (cum + c >= (unsigned)k) { bdigit_sh = 4 * t + q; bk_sh = k - (int)cum; break; }
                    cum += c;
                }
            }
        }
        __syncthreads();
        int d = bdigit_sh;
        k = bk_sh;
        prefix |= ((unsigned long long)(unsigned)d) << shift;
        plen += 8;
        unsigned ceq = hist[d];
        if (ceq == 1u) {  // unique bucket: the 100th key is determined
            for (int r = 0; r < 12; ++r) {
                unsigned long long key = keys[t + r * 256];
                if ((key >> (64 - plen)) == (prefix >> (64 - plen))) tkey_sh = key;
            }
            done = true;  // uniform (ceq is uniform)
        }
        __syncthreads();
    }
    // round 7 examines the full key (all keys unique) => tkey_sh always set
    unsigned long long T = tkey_sh;

    // ---- phase C: compact + rank + emit ----
    for (int r = 0; r < 12; ++r) {
        unsigned long long key = keys[t + r * 256];
        if (key >= T) {
            unsigned pos = atomicAdd(&scnt, 1u);  // exactly 100 total
            sel[pos] = key;
        }
    }
    __syncthreads();
    if (t < KSEL) {
        unsigned long long key = sel[t];
        int rank = 0;
        for (int p = 0; p < KSEL; ++p) rank += (sel[p] > key) ? 1 : 0;
        unsigned idx = 0xFFFFFFFFu - (unsigned)(key & 0xFFFFFFFFull);
        float conf = __uint_as_float((unsigned)(key >> 32));
        int n = b * KSEL + rank;
        confv[n] = conf;
        const float* pe = pb + (size_t)idx * 5;
        int w = idx & 31, h = (idx >> 5) & 31;  // flat = a*1024 + h*32 + w
        float x  = (sigf(pe[0]) + (float)w) * 32.0f;
        float y  = (sigf(pe[1]) + (float)h) * 32.0f;
        float bw = expf(pe[2]) * 32.0f;
        float bh = expf(pe[3]) * 32.0f;
        predc[n * 4 + 0] = x - bw * 0.5f;
        predc[n * 4 + 1] = y - bh * 0.5f;
        predc[n * 4 + 2] = x + bw * 0.5f;
        predc[n * 4 + 3] = y + bh * 0.5f;
    }
}

// ---------------------------------------------------------------------------
// k_maxiou: grid (25, 50). block (x, y): targets j in [x*256, x*256+256),
// preds i in [y*128, y*128+128) staged in LDS (boxes + precomputed areas);
// atomicMax (float-as-uint, IoU >= 0). iou via v_rcp_f32: union > 0 strictly
// here (pred areas are exp-products > 0; target boxes epsilon-fixed), ~1 ulp.
// PCHUNK=128 balances CU load: max-loaded CU runs 5x128=640 inner iters vs
// 4x200=800 at PCHUNK=200.
// blockIdx.y == 0 additionally computes paired DIoU and the smooth-L1 partial.
// ---------------------------------------------------------------------------
__global__ __launch_bounds__(256) void k_maxiou(const float* __restrict__ predc,
                                                const float* __restrict__ targc,
                                                unsigned int* __restrict__ maxiou_bits,
                                                float* __restrict__ diouv,
                                                double* __restrict__ sl1p /*[25]*/) {
    __shared__ float4 pl[PCHUNK];
    __shared__ float pa_sh[PCHUNK];
    int t = threadIdx.x;
    int j = blockIdx.x * 256 + t;
    const float4* pc4 = (const float4*)predc;
    int i0 = blockIdx.y * PCHUNK;
    if (t < PCHUNK) {
        float4 p = pc4[i0 + t];
        pl[t] = p;
        pa_sh[t] = (p.z - p.x) * (p.w - p.y);
    }
    float4 tj = ((const float4*)targc)[j];
    float ta = (tj.z - tj.x) * (tj.w - tj.y);
    __syncthreads();
    float m0 = 0.0f, m1 = 0.0f, m2 = 0.0f, m3 = 0.0f;
    #pragma unroll 2
    for (int i = 0; i < PCHUNK; i += 4) {
        {
            float4 p = pl[i];
            float w = fmaxf(fminf(p.z, tj.z) - fmaxf(p.x, tj.x), 0.0f);
            float h = fmaxf(fminf(p.w, tj.w) - fmaxf(p.y, tj.y), 0.0f);
            float in = w * h;
            m0 = fmaxf(m0, in * __builtin_amdgcn_rcpf(pa_sh[i] + ta - in));
        }
        {
            float4 p = pl[i + 1];
            float w = fmaxf(fminf(p.z, tj.z) - fmaxf(p.x, tj.x), 0.0f);
            float h = fmaxf(fminf(p.w, tj.w) - fmaxf(p.y, tj.y), 0.0f);
            float in = w * h;
            m1 = fmaxf(m1, in * __builtin_amdgcn_rcpf(pa_sh[i + 1] + ta - in));
        }
        {
            float4 p = pl[i + 2];
            float w = fmaxf(fminf(p.z, tj.z) - fmaxf(p.x, tj.x), 0.0f);
            float h = fmaxf(fminf(p.w, tj.w) - fmaxf(p.y, tj.y), 0.0f);
            float in = w * h;
            m2 = fmaxf(m2, in * __builtin_amdgcn_rcpf(pa_sh[i + 2] + ta - in));
        }
        {
            float4 p = pl[i + 3];
            float w = fmaxf(fminf(p.z, tj.z) - fmaxf(p.x, tj.x), 0.0f);
            float h = fmaxf(fminf(p.w, tj.w) - fmaxf(p.y, tj.y), 0.0f);
            float in = w * h;
            m3 = fmaxf(m3, in * __builtin_amdgcn_rcpf(pa_sh[i + 3] + ta - in));
        }
    }
    m0 = fmaxf(fmaxf(m0, m1), fmaxf(m2, m3));
    atomicMax(&maxiou_bits[j], __float_as_uint(m0));

    if (blockIdx.y == 0) {
        float4 p = pc4[j];  // paired pred for target j
        float pa = fmaxf(p.z - p.x, 0.f) * fmaxf(p.w - p.y, 0.f);
        float ta2 = fmaxf(tj.z - tj.x, 0.f) * fmaxf(tj.w - tj.y, 0.f);
        float ix1 = fmaxf(p.x, tj.x), iy1 = fmaxf(p.y, tj.y);
        float ix2 = fminf(p.z, tj.z), iy2 = fminf(p.w, tj.w);
        float inter = fmaxf(ix2 - ix1, 0.f) * fmaxf(iy2 - iy1, 0.f);
        float iou = inter / (pa + ta2 - inter + 1e-7f);
        float pcx = (p.x + p.z) * 0.5f, pcy = (p.y + p.w) * 0.5f;
        float tcx = (tj.x + tj.z) * 0.5f, tcy = (tj.y + tj.w) * 0.5f;
        float cd = (pcx - tcx) * (pcx - tcx) + (pcy - tcy) * (pcy - tcy);
        float ex1 = fminf(p.x, tj.x), ey1 = fminf(p.y, tj.y);
        float ex2 = fmaxf(p.z, tj.z), ey2 = fmaxf(p.w, tj.w);
        float dg = (ex2 - ex1) * (ex2 - ex1) + (ey2 - ey1) * (ey2 - ey1);
        diouv[j] = 1.0f - (iou - cd / (dg + 1e-7f));
        double s = 0.0;
        {
            float d0 = p.x - tj.x, d1 = p.y - tj.y, d2 = p.z - tj.z, d3 = p.w - tj.w;
            float a0 = fabsf(d0), a1 = fabsf(d1), a2 = fabsf(d2), a3 = fabsf(d3);
            s += (double)(a0 < 1.f ? 0.5f * d0 * d0 : a0 - 0.5f);
            s += (double)(a1 < 1.f ? 0.5f * d1 * d1 : a1 - 0.5f);
            s += (double)(a2 < 1.f ? 0.5f * d2 * d2 : a2 - 0.5f);
            s += (double)(a3 < 1.f ? 0.5f * d3 * d3 : a3 - 0.5f);
        }
        double v = block_reduce_sum(s);
        if (t == 0) sl1p[blockIdx.x] = v;
    }
}

// ---------------------------------------------------------------------------
// k_pair: sum over the [N,N] broadcast of good - bad. grid (25 j, 50 i).
// (1-y)^2 precomputed in LDS; raw v_sqrt_f32 (~1 ulp vs 0.28 threshold).
// ICHUNK=128 balances CU load (max CU 5x128=640 i-iters vs 3x256=768).
// Writes one double partial per block (plain array, no atomics).
// ---------------------------------------------------------------------------
__global__ __launch_bounds__(256) void k_pair(const unsigned int* __restrict__ maxiou_bits,
                                              const float* __restrict__ diouv,
                                              const float* __restrict__ confv,
                                              const double* __restrict__ sl1p,
                                              double* __restrict__ pairp /*[1250]*/) {
    __shared__ float oy2s[ICHUNK];
    __shared__ float sl1_sh;
    int t = threadIdx.x;
    int j = blockIdx.x * 256 + t;
    if (t == 0) {
        double s = 0.0;
        for (int i = 0; i < 25; ++i) s += sl1p[i];
        sl1_sh = (float)(s / 25600.0 / 512.0);
    }
    if (t < ICHUNK) {
        float oy = 1.0f - confv[blockIdx.y * ICHUNK + t];
        oy2s[t] = oy * oy;
    }
    float mj = __uint_as_float(maxiou_bits[j]);
    float dj = diouv[j];
    __syncthreads();
    float xj = (1.0f - mj) * 2.0f + dj + sl1_sh;
    float a2 = xj * xj;
    float bb = 3.5f - xj;
    float b2 = bb * bb;
    float acc0 = 0.0f, acc1 = 0.0f;
    #pragma unroll 4
    for (int i = 0; i < ICHUNK; i += 2) {
        float o0 = oy2s[i], o1 = oy2s[i + 1];
        acc0 += 2.0f * __builtin_amdgcn_sqrtf(a2 + o0)
              - 1.5f * __builtin_amdgcn_sqrtf(b2 + o0);
        acc1 += 2.0f * __builtin_amdgcn_sqrtf(a2 + o1)
              - 1.5f * __builtin_amdgcn_sqrtf(b2 + o1);
    }
    double v = block_reduce_sum((double)(acc0 + acc1));
    if (t == 0) pairp[blockIdx.x * 50 + blockIdx.y] = v;
}

// ---------------------------------------------------------------------------
// k_final: reduce 1250 pair partials + 64 negpen partials, emit scalar.
// ---------------------------------------------------------------------------
__global__ __launch_bounds__(256) void k_final(const double* __restrict__ pairp,
                                               const double* __restrict__ negp,
                                               float* __restrict__ out) {
    int t = threadIdx.x;
    double s = 0.0;
    for (int i = t; i < NPAIRBLK; i += 256) s += pairp[i];
    double ps = block_reduce_sum(s);
    double n = (t < 64) ? negp[t] : 0.0;
    double ns = block_reduce_sum(n);
    if (t == 0) {
        double mean_pair = ps / 40960000.0;                    // 6400*6400
        float losses = fmaxf((float)mean_pair + 5.25f, 0.0f);  // + 3.5*1.5
        float neg = (float)(ns / 196608.0);
        out[0] = losses + neg;
    }
}

// ---------------- launch ----------------

extern "C" void kernel_launch(void* const* d_in, const int* in_sizes, int n_in,
                              void* d_out, int out_size, void* d_ws, size_t ws_size,
                              hipStream_t stream) {
    const float* pred = (const float*)d_in[0];   // [64,3,32,32,5]
    const float* tgt  = (const float*)d_in[1];   // [64,100,4]
    float* out = (float*)d_out;

    char* ws = (char*)d_ws;
    double* negp  = (double*)ws;             // 64 doubles
    double* sl1p  = negp + 64;               // 25 (padded to 32)
    double* pairp = negp + 96;               // 1250 doubles -> ends at (96+1250)*8 = 10768
    float* fbase  = (float*)(ws + 10768);    // 16B-aligned float region
    float* predc  = fbase;                   // 25600 floats
    float* targc  = fbase + 25600;           // 25600
    float* confv  = fbase + 51200;           // 6400
    float* diouv  = fbase + 57600;           // 6400
    unsigned int* maxiou_bits = (unsigned int*)(fbase + 64000);  // 6400

    k_topk<<<64, 256, 0, stream>>>(pred, tgt, predc, targc, confv, maxiou_bits, negp);
    k_maxiou<<<dim3(25, 6400 / PCHUNK), 256, 0, stream>>>(predc, targc, maxiou_bits, diouv, sl1p);
    k_pair<<<dim3(25, 6400 / ICHUNK), 256, 0, stream>>>(maxiou_bits, diouv, confv, sl1p, pairp);
    k_final<<<1, 256, 0, stream>>>(pairp, negp, out);
}